// Round 2
// baseline (17.091 us; speedup 1.0000x reference)
//
#include <hip/hip_runtime.h>

// Partial trace of rho (8192x8192 fp32), D=2, N=13, keep qudits Q=(3,7,11).
// Big-endian digits: qudit q <-> bit (13-q); kept bit positions = {10, 6, 2}.
// out[a*8+b] = sum_t rho[(s|ka)*8192 + (s|kb)],  s = spread(t) over traced bits.
//
// Structure: 512 single-wave blocks = 32 (a, b>>1) output-pairs x 16 t-chunks.
// Each lane handles one t: loads col (b&1=0) and col+4 (b&1=1) -- same 64B
// line, so the 2nd load is an L1 hit (32768 distinct lines total ~= 2 MB).
// Wave shuffle-reduce both sums, then 2 atomicAdds per block into d_out
// (zeroed each call via hipMemsetAsync -- atomics must not accumulate
// across graph replays).

__device__ __forceinline__ unsigned spread_traced(unsigned t) {
    // Scatter 10 bits of t into positions {0,1, 3,4,5, 7,8,9, 11,12}
    return (t & 0x003u)           // t[0:2)  -> bits 0..1
         | ((t & 0x01Cu) << 1)    // t[2:5)  -> bits 3..5
         | ((t & 0x0E0u) << 2)    // t[5:8)  -> bits 7..9
         | ((t & 0x300u) << 3);   // t[8:10) -> bits 11..12
}

__global__ void __launch_bounds__(64)
ptrace_kernel(const float* __restrict__ rho, float* __restrict__ out) {
    const unsigned bid   = blockIdx.x;        // 0..511
    const unsigned pair  = bid >> 4;          // 0..31 : (a, bh)
    const unsigned chunk = bid & 15u;         // 0..15 : t-chunk
    const unsigned a     = pair >> 2;         // 0..7
    const unsigned bh    = pair & 3u;         // 0..3  (b >> 1)

    const unsigned ka  = ((a >> 2) & 1u) << 10 | ((a >> 1) & 1u) << 6 | (a & 1u) << 2;
    const unsigned kbh = ((bh >> 1) & 1u) << 10 | (bh & 1u) << 6;   // b&1 -> bit 2 handled by +4

    const unsigned t = chunk * 64u + threadIdx.x;   // 0..1023
    const unsigned s = spread_traced(t);
    const float* p = rho + (size_t)(s | ka) * 8192u + (s | kbh);

    float s0 = p[0];   // b = 2*bh + 0
    float s1 = p[4];   // b = 2*bh + 1  (same 64B line)

    // wave64 butterfly reduction of both sums
    #pragma unroll
    for (int off = 32; off > 0; off >>= 1) {
        s0 += __shfl_xor(s0, off, 64);
        s1 += __shfl_xor(s1, off, 64);
    }

    if (threadIdx.x == 0) {
        atomicAdd(&out[a * 8u + bh * 2u + 0u], s0);
        atomicAdd(&out[a * 8u + bh * 2u + 1u], s1);
    }
}

extern "C" void kernel_launch(void* const* d_in, const int* in_sizes, int n_in,
                              void* d_out, int out_size, void* d_ws, size_t ws_size,
                              hipStream_t stream) {
    const float* rho = (const float*)d_in[0];
    float* out = (float*)d_out;
    // Atomic accumulation target must start at zero on EVERY call
    // (harness does not re-poison d_out between graph replays).
    hipMemsetAsync(out, 0, 64 * sizeof(float), stream);
    ptrace_kernel<<<512, 64, 0, stream>>>(rho, out);
}

// Round 3
// 9.754 us; speedup vs baseline: 1.7523x; 1.7523x over previous
//
#include <hip/hip_runtime.h>

// Partial trace of rho (8192x8192 fp32), D=2, N=13, keep qudits Q=(3,7,11).
// Big-endian digits: qudit q <-> bit (13-q); kept bit positions = {10, 6, 2}.
// out[a*8+b] = sum_t rho[(s|ka)*8192 + (s|kb)],  s = spread(t) over traced bits.
//
// Single dispatch (round-2 showed a 2nd dispatch costs ~7us of graph floor).
// Block = one (a, b>>1) output pair: 32 blocks x 1024 threads, one t each.
// Thread loads col and col+4 (same 64B line) -> 32768 distinct line misses
// total (the minimum: lines are uniquely keyed by (a, s, b>>1)), all issued
// in one latency window. In-block reduction only; no atomics, no memset.

__device__ __forceinline__ unsigned spread_traced(unsigned t) {
    // Scatter 10 bits of t into positions {0,1, 3,4,5, 7,8,9, 11,12}
    return (t & 0x003u)           // t[0:2)  -> bits 0..1
         | ((t & 0x01Cu) << 1)    // t[2:5)  -> bits 3..5
         | ((t & 0x0E0u) << 2)    // t[5:8)  -> bits 7..9
         | ((t & 0x300u) << 3);   // t[8:10) -> bits 11..12
}

__global__ void __launch_bounds__(1024)
ptrace_kernel(const float* __restrict__ rho, float* __restrict__ out) {
    const unsigned pair = blockIdx.x;         // 0..31 : (a, bh)
    const unsigned a    = pair >> 2;          // 0..7
    const unsigned bh   = pair & 3u;          // 0..3  (b >> 1)

    const unsigned ka  = ((a >> 2) & 1u) << 10 | ((a >> 1) & 1u) << 6 | (a & 1u) << 2;
    const unsigned kbh = ((bh >> 1) & 1u) << 10 | (bh & 1u) << 6;  // b&1 -> +4 (bit 2)

    const unsigned t = threadIdx.x;           // 0..1023
    const unsigned s = spread_traced(t);
    const float* p = rho + (size_t)(s | ka) * 8192u + (s | kbh);

    float s0 = p[0];   // b = 2*bh + 0
    float s1 = p[4];   // b = 2*bh + 1  (same 64B cache line)

    // wave64 butterfly reduction
    #pragma unroll
    for (int off = 32; off > 0; off >>= 1) {
        s0 += __shfl_xor(s0, off, 64);
        s1 += __shfl_xor(s1, off, 64);
    }

    // cross-wave reduction: 16 waves -> LDS -> first-wave shuffle
    __shared__ float ws0[16], ws1[16];
    const unsigned lane = threadIdx.x & 63u;
    const unsigned wid  = threadIdx.x >> 6;
    if (lane == 0) { ws0[wid] = s0; ws1[wid] = s1; }
    __syncthreads();

    if (threadIdx.x < 16u) {
        float r0 = ws0[threadIdx.x];
        float r1 = ws1[threadIdx.x];
        #pragma unroll
        for (int off = 8; off > 0; off >>= 1) {
            r0 += __shfl_xor(r0, off, 64);
            r1 += __shfl_xor(r1, off, 64);
        }
        if (threadIdx.x == 0) {
            out[a * 8u + bh * 2u + 0u] = r0;
            out[a * 8u + bh * 2u + 1u] = r1;
        }
    }
}

extern "C" void kernel_launch(void* const* d_in, const int* in_sizes, int n_in,
                              void* d_out, int out_size, void* d_ws, size_t ws_size,
                              hipStream_t stream) {
    const float* rho = (const float*)d_in[0];
    float* out = (float*)d_out;
    ptrace_kernel<<<32, 1024, 0, stream>>>(rho, out);
}